// Round 17
// baseline (377.571 us; speedup 1.0000x reference)
//
#include <hip/hip_runtime.h>
#include <math.h>

#define SCAN_B 1024
#define LDST 40   // LDS row stride in bf16 elems (32 data + 8 pad)

typedef __attribute__((ext_vector_type(8))) short short8v;
typedef __attribute__((ext_vector_type(8))) unsigned short ushort8v;
typedef __attribute__((ext_vector_type(4))) float f32x4;

static inline int ceil_div_i(long long a, int b) { return (int)((a + b - 1) / b); }

__device__ __forceinline__ unsigned short f2bf(float x) {
    unsigned int u = __float_as_uint(x);
    u += 0x7fffu + ((u >> 16) & 1u);   // round-to-nearest-even
    return (unsigned short)(u >> 16);
}
__device__ __forceinline__ float bf2f(unsigned short h) {
    return __uint_as_float(((unsigned int)h) << 16);
}
__device__ __forceinline__ ushort8v zero8() {
    ushort8v z;
#pragma unroll
    for (int e = 0; e < 8; e++) z[e] = 0;
    return z;
}

// ---------------- CSR construction ----------------

__global__ __launch_bounds__(256) void k_count(const int* __restrict__ dst, int E,
                                               int* __restrict__ cnt) {
    int i = blockIdx.x * blockDim.x + threadIdx.x;
    if (i < E) atomicAdd(&cnt[dst[i]], 1);
}

__global__ __launch_bounds__(256) void k_dinv(const int* __restrict__ cnt,
                                              float* __restrict__ dinv, int N) {
    int i = blockIdx.x * blockDim.x + threadIdx.x;
    if (i < N) dinv[i] = (float)(1.0 / sqrt((double)(cnt[i] + 1)));
}

__global__ __launch_bounds__(256) void k_scan1(const int* __restrict__ cnt,
                                               int* __restrict__ rowptr,
                                               int* __restrict__ bsum, int N) {
    __shared__ int s[256];
    int tid = threadIdx.x;
    int base = blockIdx.x * SCAN_B + tid * 4;
    int a0 = (base + 0 < N) ? cnt[base + 0] : 0;
    int a1 = (base + 1 < N) ? cnt[base + 1] : 0;
    int a2 = (base + 2 < N) ? cnt[base + 2] : 0;
    int a3 = (base + 3 < N) ? cnt[base + 3] : 0;
    int tsum = a0 + a1 + a2 + a3;
    s[tid] = tsum;
    __syncthreads();
    for (int off = 1; off < 256; off <<= 1) {
        int val = 0;
        if (tid >= off) val = s[tid - off];
        __syncthreads();
        if (tid >= off) s[tid] += val;
        __syncthreads();
    }
    int texcl = s[tid] - tsum;
    if (tid == 255) bsum[blockIdx.x] = s[255];
    if (base + 0 < N) rowptr[base + 0] = texcl;
    if (base + 1 < N) rowptr[base + 1] = texcl + a0;
    if (base + 2 < N) rowptr[base + 2] = texcl + a0 + a1;
    if (base + 3 < N) rowptr[base + 3] = texcl + a0 + a1 + a2;
}

__global__ __launch_bounds__(256) void k_scan2(int* __restrict__ bsum, int NB) {
    __shared__ int s[256];
    int tid = threadIdx.x;
    int v = (tid < NB) ? bsum[tid] : 0;
    s[tid] = v;
    __syncthreads();
    for (int off = 1; off < 256; off <<= 1) {
        int val = 0;
        if (tid >= off) val = s[tid - off];
        __syncthreads();
        if (tid >= off) s[tid] += val;
        __syncthreads();
    }
    if (tid < NB) bsum[tid] = s[tid] - v;
}

// also pre-loads fill[] with the final rowptr (so k_fill's atomicAdd returns the slot)
__global__ __launch_bounds__(256) void k_scan3(int* __restrict__ rowptr,
                                               const int* __restrict__ bsum,
                                               int* __restrict__ fill, int N, int E) {
    int i = blockIdx.x * blockDim.x + threadIdx.x;
    if (i < N) {
        int r = rowptr[i] + bsum[i >> 10];
        rowptr[i] = r;
        fill[i] = r;
    }
    if (i == 0) rowptr[N] = E;
}

// fill: 1 edge/thread (max concurrency for latency-bound scatter); col is uint16
__global__ __launch_bounds__(256) void k_fill(const int* __restrict__ src,
                                              const int* __restrict__ dst, int E,
                                              int* __restrict__ fill,
                                              unsigned short* __restrict__ col) {
    int e = blockIdx.x * blockDim.x + threadIdx.x;
    if (e >= E) return;
    int s = src[e], d = dst[e];
    int idx = atomicAdd(&fill[d], 1);
    col[idx] = (unsigned short)s;
}

// ---------------- scale+pad x -> bf16: Y[v][c] = bf16(dinv[v]*x[v][c]), stride XS ------

__global__ __launch_bounds__(256) void k_xscale(const float* __restrict__ x,
                                                const float* __restrict__ dinv,
                                                unsigned short* __restrict__ xb,
                                                int N, int F, int XS) {
    int i = blockIdx.x * blockDim.x + threadIdx.x;
    int v = i / XS, c = i - v * XS;
    if (v >= N) return;
    float val = (c < F) ? dinv[v] * x[(size_t)v * F + c] : 0.f;
    xb[i] = f2bf(val);
}

// ---------------- gather: S[v] = Y[v] + sum_j Y[col[j]]  (unweighted) ----------------
// Lane = (slot, chunk): SLOTS edges at once, CHUNKS lanes x 8 bf16 elems each.
// Cross-slot shfl reduce at end. Output: hi/lo bf16 planes Th, Tl (rows stride KPf).

template <int CHUNKS, int SLOTS, int UNR>
__global__ __launch_bounds__(256) void k_gather_s(const unsigned short* __restrict__ Xb,
                                                  const int* __restrict__ rowptr,
                                                  const unsigned short* __restrict__ col,
                                                  unsigned short* __restrict__ Th,
                                                  unsigned short* __restrict__ Tl,
                                                  int N, int XS, int KPf) {
    const int v = blockIdx.x * 4 + (threadIdx.x >> 6);
    const int lane = threadIdx.x & 63;
    if (v >= N) return;
    constexpr int VW = 8;
    const int slot = lane / CHUNKS;
    const int chunk = lane - slot * CHUNKS;
    const bool act = lane < CHUNKS * SLOTS;
    const int f0 = chunk * VW;

    float acc[VW];
#pragma unroll
    for (int u = 0; u < VW; u++) acc[u] = 0.f;
    if (slot == 0) {   // self term, coefficient 1
        ushort8v h = *(const ushort8v*)(Xb + (size_t)v * XS + f0);
#pragma unroll
        for (int u = 0; u < VW; u++) acc[u] = bf2f(h[u]);
    }

    const int beg = rowptr[v], end = rowptr[v + 1];
    for (int jb = beg; jb < end; jb += 64) {
        const int nj = min(64, end - jb);
        int ec = 0;
        if (lane < nj) ec = (int)col[jb + lane];
        for (int e = 0; e < nj; e += SLOTS * UNR) {
            int cs[UNR];
            bool vs[UNR];
#pragma unroll
            for (int u = 0; u < UNR; u++) {
                int srcl = e + u * SLOTS + slot;
                vs[u] = act && (srcl < nj);
                cs[u] = __shfl(ec, srcl & 63);
            }
            ushort8v xv[UNR];
#pragma unroll
            for (int u = 0; u < UNR; u++) {
                xv[u] = zero8();
                if (vs[u]) xv[u] = *(const ushort8v*)(Xb + (size_t)cs[u] * XS + f0);
            }
#pragma unroll
            for (int u = 0; u < UNR; u++)
#pragma unroll
                for (int k2 = 0; k2 < VW; k2++)
                    acc[k2] += bf2f(xv[u][k2]);
        }
    }

    // reduce across slots (valid on slot 0)
#pragma unroll
    for (int k2 = 0; k2 < VW; k2++) {
        float t2 = acc[k2];
#pragma unroll
        for (int s2 = 1; s2 < SLOTS; s2++) t2 += __shfl(acc[k2], chunk + s2 * CHUNKS);
        acc[k2] = t2;
    }

    if (slot == 0 && f0 < KPf) {
        ushort8v h8, l8;
#pragma unroll
        for (int u = 0; u < VW; u++) {
            unsigned short hh = f2bf(acc[u]);
            h8[u] = hh;
            l8[u] = f2bf(acc[u] - bf2f(hh));
        }
        *(ushort8v*)(Th + (size_t)v * KPf + f0) = h8;   // pad lanes write exact zeros
        *(ushort8v*)(Tl + (size_t)v * KPf + f0) = l8;
    }
}

// ---------------- W preprocess: transpose + split into bf16 hi/lo, k-padded to KP --------

__global__ __launch_bounds__(256) void k_wsplit(const float* __restrict__ W,
                                                unsigned short* __restrict__ Wth,
                                                unsigned short* __restrict__ Wtl,
                                                int K, int Fout, int KP) {
    int i = blockIdx.x * blockDim.x + threadIdx.x;
    if (i >= Fout * KP) return;
    int c = i / KP, k = i - c * KP;
    float w = (k < K) ? W[(size_t)k * Fout + c] : 0.f;
    unsigned short h = f2bf(w);
    Wth[i] = h;
    Wtl[i] = f2bf(w - bf2f(h));
}

// ---------------- split-bf16 MFMA GEMM, A-direct, full-width tile ----------------
// Block = 64 rows x CT cols (CT = 16*NJ2 covers ALL of Fout -> A fetched exactly once).
// 4 waves, each owns one 16-row group across all CT cols. A fragments stream straight
// from global hi/lo planes (64B coalesced); B chunk staged in LDS per 32-k chunk.
// D = Al*Bh + Ah*Bl + Ah*Bh. X' = relu(dinv[row]*(S@W)+bias).
// MODE 0: store bf16 Y' = dinv[row]*X' (row stride CSbf, pad cols zeroed).
// MODE 1: per-graph max pool of X' via atomicMax (f32 G).

template <int NJ2, int MODE>
__global__ __launch_bounds__(256) void k_gemm_fw(
    const unsigned short* __restrict__ Ahp, const unsigned short* __restrict__ Alp, int KPf,
    const unsigned short* __restrict__ Bth, const unsigned short* __restrict__ Btl,
    const float* __restrict__ bias, const float* __restrict__ dinvp,
    unsigned short* __restrict__ Cb, int CSbf,
    const int* __restrict__ batch, float* __restrict__ G,
    int N, int KP, int Fout) {
    constexpr int CT = 16 * NJ2;                 // 96 / 160 / 320
    __shared__ unsigned short sBh[CT * LDST];
    __shared__ unsigned short sBl[CT * LDST];
    __shared__ int sBatch[64];

    const int t = threadIdx.x;
    const int r0 = blockIdx.x * 64;
    const int lane = t & 63;
    const int wv = t >> 6;
    const int l15 = lane & 15;
    const int lg = lane >> 4;
    const int nt = KP >> 5;

    if (MODE == 1 && t < 64) sBatch[t] = (r0 + t < N) ? batch[r0 + t] : -1;

    const int row = r0 + wv * 16 + l15;
    const bool rok = row < N;
    const unsigned short* aH = Ahp + (size_t)row * KPf;
    const unsigned short* aL = Alp + (size_t)row * KPf;

    f32x4 acc[NJ2];
#pragma unroll
    for (int j = 0; j < NJ2; j++) acc[j] = (f32x4){0.f, 0.f, 0.f, 0.f};

    for (int tc = 0; tc < nt; ++tc) {
        const int kk = tc * 32;
        // ---- stage B chunk (both planes) into LDS ----
        for (int idx = t; idx < CT * 4; idx += 256) {
            int brow = idx >> 2, seg = idx & 3;
            ushort8v h = zero8(), l = zero8();
            if (brow < Fout) {
                h = *(const ushort8v*)(Bth + (size_t)brow * KP + kk + seg * 8);
                l = *(const ushort8v*)(Btl + (size_t)brow * KP + kk + seg * 8);
            }
            int boff = brow * LDST + seg * 8;
            *(ushort8v*)&sBh[boff] = h;
            *(ushort8v*)&sBl[boff] = l;
        }
        __syncthreads();

        // ---- A fragments direct from global (64B coalesced per 16-row group) ----
        const int gk = kk + lg * 8;
        const bool kok = rok && (gk < KPf);
        short8v Ah_ = kok ? *(const short8v*)(aH + gk) : (short8v)zero8();
        short8v Al_ = kok ? *(const short8v*)(aL + gk) : (short8v)zero8();

#pragma unroll
        for (int j = 0; j < NJ2; j++) {
            int co = (j * 16 + l15) * LDST + lg * 8;
            short8v bh = *(const short8v*)&sBh[co];
            short8v bl = *(const short8v*)&sBl[co];
            acc[j] = __builtin_amdgcn_mfma_f32_16x16x32_bf16(Al_, bh, acc[j], 0, 0, 0);
            acc[j] = __builtin_amdgcn_mfma_f32_16x16x32_bf16(Ah_, bl, acc[j], 0, 0, 0);
            acc[j] = __builtin_amdgcn_mfma_f32_16x16x32_bf16(Ah_, bh, acc[j], 0, 0, 0);
        }
        __syncthreads();
    }

    // per-thread row scales (C/D layout m89-verified: col = lane&15, row = (lane>>4)*4 + reg)
    float drw[4];
#pragma unroll
    for (int q = 0; q < 4; q++) {
        int gr = r0 + wv * 16 + (lane >> 4) * 4 + q;
        drw[q] = (gr < N) ? dinvp[gr] : 0.f;
    }

    if (MODE == 0) {
#pragma unroll
        for (int j = 0; j < NJ2; j++) {
            int gc = j * 16 + l15;
            if (gc >= CSbf) continue;
            float bv = (gc < Fout) ? bias[gc] : 0.f;
            int rb = r0 + wv * 16 + (lane >> 4) * 4;
#pragma unroll
            for (int q = 0; q < 4; q++) {
                int gr = rb + q;
                if (gr >= N) continue;
                float dr = drw[q];
                float vv = (gc < Fout) ? fmaxf(fmaf(acc[j][q], dr, bv), 0.f) * dr : 0.f;
                Cb[(size_t)gr * CSbf + gc] = f2bf(vv);
            }
        }
    } else {
#pragma unroll
        for (int j = 0; j < NJ2; j++) {
            int gc = j * 16 + l15;
            if (gc >= Fout) continue;
            float bv = bias[gc];
            int lr = wv * 16 + (lane >> 4) * 4;
            int gcur = -1;
            float vmax = 0.f;
#pragma unroll
            for (int q = 0; q < 4; q++) {
                int g = sBatch[lr + q];
                float vv = fmaxf(fmaf(acc[j][q], drw[q], bv), 0.f);
                if (g < 0) continue;
                if (g != gcur) {
                    if (gcur >= 0)
                        atomicMax((int*)&G[(size_t)gcur * Fout + gc], __float_as_int(vmax));
                    gcur = g;
                    vmax = vv;
                } else {
                    vmax = fmaxf(vmax, vv);
                }
            }
            if (gcur >= 0) atomicMax((int*)&G[(size_t)gcur * Fout + gc], __float_as_int(vmax));
        }
    }
}

// ---------------- fc_g1: C[M,Nout] = relu(A@W + b); 2 rows x 256 cols per block ----------

__global__ __launch_bounds__(256) void k_fc1(const float* __restrict__ A,
                                             const float* __restrict__ W,
                                             const float* __restrict__ bias,
                                             float* __restrict__ C,
                                             int M, int K, int Nout) {
    __shared__ float sA[2 * 304];
    const int t = threadIdx.x;
    const int m0 = blockIdx.x * 2;
    const int oc = blockIdx.y * 256 + t;

    for (int i = t; i < 2 * K; i += 256) {
        int r = i / K, k = i - r * K;
        sA[r * 304 + k] = (m0 + r < M) ? A[(size_t)(m0 + r) * K + k] : 0.f;
    }
    __syncthreads();

    float acc0 = 0.f, acc1 = 0.f;
    int k = 0;
    for (; k + 8 <= K; k += 8) {
        float w[8];
#pragma unroll
        for (int u = 0; u < 8; u++) w[u] = W[(size_t)(k + u) * Nout + oc];
#pragma unroll
        for (int u = 0; u < 8; u++) {
            acc0 = fmaf(sA[k + u], w[u], acc0);
            acc1 = fmaf(sA[304 + k + u], w[u], acc1);
        }
    }
    for (; k < K; k++) {
        float w = W[(size_t)k * Nout + oc];
        acc0 = fmaf(sA[k], w, acc0);
        acc1 = fmaf(sA[304 + k], w, acc1);
    }
    float bv = bias[oc];
    if (m0 < M) C[(size_t)m0 * Nout + oc] = fmaxf(acc0 + bv, 0.f);
    if (m0 + 1 < M) C[(size_t)(m0 + 1) * Nout + oc] = fmaxf(acc1 + bv, 0.f);
}

// ---------------- fc_g2: split-K partial (KS=256) + deterministic reduce ----------------

__global__ __launch_bounds__(256) void k_fc2p(const float* __restrict__ A,
                                              const float* __restrict__ W,
                                              float* __restrict__ P,
                                              int M, int K, int Nout) {
    __shared__ float sA[2 * 256];
    const int t = threadIdx.x;
    const int m0 = blockIdx.x * 2;
    const int sk = blockIdx.y;
    const int k0 = sk * 256;
    const int row = t >> 7;
    const int oc = t & 127;

    for (int i = t; i < 2 * 256; i += 256) {
        int r = i >> 8, k = i & 255;
        sA[i] = (m0 + r < M) ? A[(size_t)(m0 + r) * K + k0 + k] : 0.f;
    }
    __syncthreads();

    const float* a = sA + row * 256;
    float acc = 0.f;
    for (int k = 0; k < 256; k += 8) {
        float w[8];
#pragma unroll
        for (int u = 0; u < 8; u++) w[u] = W[(size_t)(k0 + k + u) * Nout + oc];
#pragma unroll
        for (int u = 0; u < 8; u++) acc = fmaf(a[k + u], w[u], acc);
    }
    int m = m0 + row;
    if (m < M) P[((size_t)sk * M + m) * Nout + oc] = acc;
}

__global__ __launch_bounds__(256) void k_fc2r(const float* __restrict__ P,
                                              const float* __restrict__ bias,
                                              float* __restrict__ C,
                                              int M, int Nout, int SK) {
    int i = blockIdx.x * blockDim.x + threadIdx.x;
    if (i >= M * Nout) return;
    int oc = i % Nout;
    float acc = bias[oc];
    for (int s2 = 0; s2 < SK; s2++) acc += P[(size_t)s2 * M * Nout + i];
    C[i] = acc;
}

// ---------------- launch ----------------

extern "C" void kernel_launch(void* const* d_in, const int* in_sizes, int n_in,
                              void* d_out, int out_size, void* d_ws, size_t ws_size,
                              hipStream_t stream) {
    const float* x     = (const float*)d_in[0];
    const int*   ei    = (const int*)d_in[1];
    const int*   batch = (const int*)d_in[2];
    const float* W1 = (const float*)d_in[3];
    const float* b1 = (const float*)d_in[4];
    const float* W2 = (const float*)d_in[5];
    const float* b2 = (const float*)d_in[6];
    const float* W3 = (const float*)d_in[7];
    const float* b3 = (const float*)d_in[8];
    const float* Wg1 = (const float*)d_in[9];
    const float* bg1 = (const float*)d_in[10];
    const float* Wg2 = (const float*)d_in[11];
    const float* bg2 = (const float*)d_in[12];

    const int N  = in_sizes[2];          // 50000 (< 65536: col fits uint16)
    const int E  = in_sizes[1] / 2;      // 800000
    const int F1 = in_sizes[4];          // 75
    const int F2 = in_sizes[6];          // 150
    const int F3 = in_sizes[8];          // 300
    const int H1 = in_sizes[10];         // 1024
    const int OC = in_sizes[12];         // 128
    const int NG = out_size / OC;        // 256
    const int FIN = in_sizes[3] / F1;    // 75

    const int KP1 = 96,  KPf1 = 80;      // K=75 padded (GEMM loop / A-plane stride)
    const int KP3 = 160, KPf3 = 152;     // K=150 padded
    const int XS0 = 80;                  // x bf16 (pre-scaled) row stride
    const int HS1 = 80;                  // Y1 bf16 row stride
    const int HS2 = 152;                 // Y2 bf16 row stride

    const int* src = ei;
    const int* dst = ei + E;

    char* base = (char*)d_ws;
    size_t off = 0;
    auto alloc = [&](size_t bytes) -> void* {
        void* p = base + off;
        off = (off + bytes + 255) & ~(size_t)255;
        return p;
    };
    int*   cnt    = (int*)alloc((size_t)N * 4);
    int*   fill   = (int*)alloc((size_t)N * 4);
    int*   rowptr = (int*)alloc((size_t)(N + 1) * 4);
    float* dinv   = (float*)alloc((size_t)N * 4);
    int*   bsum   = (int*)alloc(256 * 4);
    unsigned short* col = (unsigned short*)alloc((size_t)E * 2);
    unsigned short* W1th = (unsigned short*)alloc((size_t)F1 * KP1 * 2);
    unsigned short* W1tl = (unsigned short*)alloc((size_t)F1 * KP1 * 2);
    unsigned short* W2th = (unsigned short*)alloc((size_t)F2 * KP1 * 2);
    unsigned short* W2tl = (unsigned short*)alloc((size_t)F2 * KP1 * 2);
    unsigned short* W3th = (unsigned short*)alloc((size_t)F3 * KP3 * 2);
    unsigned short* W3tl = (unsigned short*)alloc((size_t)F3 * KP3 * 2);
    float* Gb  = (float*)alloc((size_t)NG * F3 * 4);
    float* g1  = (float*)alloc((size_t)NG * H1 * 4);
    float* P2  = (float*)alloc((size_t)4 * NG * OC * 4);                // split-K partials
    unsigned short* TgH = (unsigned short*)alloc((size_t)N * KPf3 * 2); // 15.2 MB hi plane
    unsigned short* TgL = (unsigned short*)alloc((size_t)N * KPf3 * 2); // 15.2 MB lo plane
    unsigned short* Xb  = (unsigned short*)alloc((size_t)N * XS0 * 2);  // 8 MB bf16 scaled x
    unsigned short* H1b = (unsigned short*)alloc((size_t)N * HS1 * 2);  // 8 MB bf16
    unsigned short* H2b = (unsigned short*)alloc((size_t)N * HS2 * 2);  // 15.2 MB bf16

    hipMemsetAsync(cnt, 0, (size_t)N * 4, stream);
    hipMemsetAsync(Gb, 0, (size_t)NG * F3 * 4, stream);

    // ---- CSR ----
    k_count<<<ceil_div_i(E, 256), 256, 0, stream>>>(dst, E, cnt);
    k_dinv<<<ceil_div_i(N, 256), 256, 0, stream>>>(cnt, dinv, N);
    int NB = ceil_div_i(N, SCAN_B);
    k_scan1<<<NB, 256, 0, stream>>>(cnt, rowptr, bsum, N);
    k_scan2<<<1, 256, 0, stream>>>(bsum, NB);
    k_scan3<<<ceil_div_i(N, 256), 256, 0, stream>>>(rowptr, bsum, fill, N, E);
    k_fill<<<ceil_div_i(E, 256), 256, 0, stream>>>(src, dst, E, fill, col);

    // ---- weight splits + scaled-x (small) ----
    k_wsplit<<<ceil_div_i((long long)F1 * KP1, 256), 256, 0, stream>>>(W1, W1th, W1tl, FIN, F1, KP1);
    k_wsplit<<<ceil_div_i((long long)F2 * KP1, 256), 256, 0, stream>>>(W2, W2th, W2tl, F1, F2, KP1);
    k_wsplit<<<ceil_div_i((long long)F3 * KP3, 256), 256, 0, stream>>>(W3, W3th, W3tl, F2, F3, KP3);
    k_xscale<<<ceil_div_i((long long)N * XS0, 256), 256, 0, stream>>>(x, dinv, Xb, N, FIN, XS0);

    dim3 blk(256);
    int gw = ceil_div_i(N, 4);
    int gx = ceil_div_i(N, 64);   // 64 rows per GEMM block

    // conv1: gather Xb (10 chunks x 6 slots) -> TgH/TgL stride 80; GEMM CT=96 covers 75
    k_gather_s<10, 6, 2><<<gw, blk, 0, stream>>>(Xb, rowptr, col, TgH, TgL, N, XS0, KPf1);
    k_gemm_fw<6, 0><<<gx, blk, 0, stream>>>(TgH, TgL, KPf1, W1th, W1tl, b1, dinv,
                                            H1b, HS1, nullptr, nullptr, N, KP1, F1);
    // conv2: gather Y1 -> TgH/TgL stride 80; GEMM CT=160 covers 150
    k_gather_s<10, 6, 2><<<gw, blk, 0, stream>>>(H1b, rowptr, col, TgH, TgL, N, HS1, KPf1);
    k_gemm_fw<10, 0><<<gx, blk, 0, stream>>>(TgH, TgL, KPf1, W2th, W2tl, b2, dinv,
                                             H2b, HS2, nullptr, nullptr, N, KP1, F2);
    // conv3: gather Y2 (19 chunks x 3 slots) -> stride 152; GEMM CT=320, fused pool
    k_gather_s<19, 3, 4><<<gw, blk, 0, stream>>>(H2b, rowptr, col, TgH, TgL, N, HS2, KPf3);
    k_gemm_fw<20, 1><<<gx, blk, 0, stream>>>(TgH, TgL, KPf3, W3th, W3tl, b3, dinv,
                                             nullptr, 0, batch, Gb, N, KP3, F3);

    // fc_g1: 2 rows x 256 cols per block -> grid (128, 4) = 512 blocks
    {
        dim3 g(ceil_div_i(NG, 2), H1 / 256);
        k_fc1<<<g, 256, 0, stream>>>(Gb, Wg1, bg1, g1, NG, F3, H1);
    }
    // fc_g2: split-K=4 partials (512 blocks) + deterministic reduce
    {
        dim3 g(ceil_div_i(NG, 2), 4);
        k_fc2p<<<g, 256, 0, stream>>>(g1, Wg2, P2, NG, H1, OC);
        k_fc2r<<<ceil_div_i((long long)NG * OC, 256), 256, 0, stream>>>(
            P2, bg2, (float*)d_out, NG, OC, 4);
    }
}

// Round 18
// 336.959 us; speedup vs baseline: 1.1205x; 1.1205x over previous
//
#include <hip/hip_runtime.h>
#include <math.h>

#define SCAN_B 1024
#define LDST 40   // LDS row stride in bf16 elems (32 data + 8 pad) — round-11/15 proven

typedef __attribute__((ext_vector_type(8))) short short8v;
typedef __attribute__((ext_vector_type(8))) unsigned short ushort8v;
typedef __attribute__((ext_vector_type(4))) float f32x4;

static inline int ceil_div_i(long long a, int b) { return (int)((a + b - 1) / b); }

__device__ __forceinline__ unsigned short f2bf(float x) {
    unsigned int u = __float_as_uint(x);
    u += 0x7fffu + ((u >> 16) & 1u);   // round-to-nearest-even
    return (unsigned short)(u >> 16);
}
__device__ __forceinline__ float bf2f(unsigned short h) {
    return __uint_as_float(((unsigned int)h) << 16);
}
__device__ __forceinline__ ushort8v zero8() {
    ushort8v z;
#pragma unroll
    for (int e = 0; e < 8; e++) z[e] = 0;
    return z;
}

// ---------------- CSR construction ----------------

__global__ __launch_bounds__(256) void k_count(const int* __restrict__ dst, int E,
                                               int* __restrict__ cnt) {
    int i = blockIdx.x * blockDim.x + threadIdx.x;
    if (i < E) atomicAdd(&cnt[dst[i]], 1);
}

__global__ __launch_bounds__(256) void k_dinv(const int* __restrict__ cnt,
                                              float* __restrict__ dinv, int N) {
    int i = blockIdx.x * blockDim.x + threadIdx.x;
    if (i < N) dinv[i] = (float)(1.0 / sqrt((double)(cnt[i] + 1)));
}

__global__ __launch_bounds__(256) void k_scan1(const int* __restrict__ cnt,
                                               int* __restrict__ rowptr,
                                               int* __restrict__ bsum, int N) {
    __shared__ int s[256];
    int tid = threadIdx.x;
    int base = blockIdx.x * SCAN_B + tid * 4;
    int a0 = (base + 0 < N) ? cnt[base + 0] : 0;
    int a1 = (base + 1 < N) ? cnt[base + 1] : 0;
    int a2 = (base + 2 < N) ? cnt[base + 2] : 0;
    int a3 = (base + 3 < N) ? cnt[base + 3] : 0;
    int tsum = a0 + a1 + a2 + a3;
    s[tid] = tsum;
    __syncthreads();
    for (int off = 1; off < 256; off <<= 1) {
        int val = 0;
        if (tid >= off) val = s[tid - off];
        __syncthreads();
        if (tid >= off) s[tid] += val;
        __syncthreads();
    }
    int texcl = s[tid] - tsum;
    if (tid == 255) bsum[blockIdx.x] = s[255];
    if (base + 0 < N) rowptr[base + 0] = texcl;
    if (base + 1 < N) rowptr[base + 1] = texcl + a0;
    if (base + 2 < N) rowptr[base + 2] = texcl + a0 + a1;
    if (base + 3 < N) rowptr[base + 3] = texcl + a0 + a1 + a2;
}

__global__ __launch_bounds__(256) void k_scan2(int* __restrict__ bsum, int NB) {
    __shared__ int s[256];
    int tid = threadIdx.x;
    int v = (tid < NB) ? bsum[tid] : 0;
    s[tid] = v;
    __syncthreads();
    for (int off = 1; off < 256; off <<= 1) {
        int val = 0;
        if (tid >= off) val = s[tid - off];
        __syncthreads();
        if (tid >= off) s[tid] += val;
        __syncthreads();
    }
    if (tid < NB) bsum[tid] = s[tid] - v;
}

// also pre-loads fill[] with the final rowptr (so k_fill's atomicAdd returns the slot)
__global__ __launch_bounds__(256) void k_scan3(int* __restrict__ rowptr,
                                               const int* __restrict__ bsum,
                                               int* __restrict__ fill, int N, int E) {
    int i = blockIdx.x * blockDim.x + threadIdx.x;
    if (i < N) {
        int r = rowptr[i] + bsum[i >> 10];
        rowptr[i] = r;
        fill[i] = r;
    }
    if (i == 0) rowptr[N] = E;
}

// fill: 1 edge/thread (max concurrency for latency-bound scatter); col is uint16
__global__ __launch_bounds__(256) void k_fill(const int* __restrict__ src,
                                              const int* __restrict__ dst, int E,
                                              int* __restrict__ fill,
                                              unsigned short* __restrict__ col) {
    int e = blockIdx.x * blockDim.x + threadIdx.x;
    if (e >= E) return;
    int s = src[e], d = dst[e];
    int idx = atomicAdd(&fill[d], 1);
    col[idx] = (unsigned short)s;
}

// ---------------- scale+pad x -> bf16: Y[v][c] = bf16(dinv[v]*x[v][c]), stride XS ------

__global__ __launch_bounds__(256) void k_xscale(const float* __restrict__ x,
                                                const float* __restrict__ dinv,
                                                unsigned short* __restrict__ xb,
                                                int N, int F, int XS) {
    int i = blockIdx.x * blockDim.x + threadIdx.x;
    int v = i / XS, c = i - v * XS;
    if (v >= N) return;
    float val = (c < F) ? dinv[v] * x[(size_t)v * F + c] : 0.f;
    xb[i] = f2bf(val);
}

// ---------------- gather: S[v] = Y[v] + sum_j Y[col[j]]  (unweighted) ----------------
// Lane = (slot, chunk): SLOTS edges at once, CHUNKS lanes x 8 bf16 elems each.
// Cross-slot shfl reduce at end. Output: hi/lo bf16 planes Th, Tl (rows stride KPf).

template <int CHUNKS, int SLOTS, int UNR>
__global__ __launch_bounds__(256) void k_gather_s(const unsigned short* __restrict__ Xb,
                                                  const int* __restrict__ rowptr,
                                                  const unsigned short* __restrict__ col,
                                                  unsigned short* __restrict__ Th,
                                                  unsigned short* __restrict__ Tl,
                                                  int N, int XS, int KPf) {
    const int v = blockIdx.x * 4 + (threadIdx.x >> 6);
    const int lane = threadIdx.x & 63;
    if (v >= N) return;
    constexpr int VW = 8;
    const int slot = lane / CHUNKS;
    const int chunk = lane - slot * CHUNKS;
    const bool act = lane < CHUNKS * SLOTS;
    const int f0 = chunk * VW;

    float acc[VW];
#pragma unroll
    for (int u = 0; u < VW; u++) acc[u] = 0.f;
    if (slot == 0) {   // self term, coefficient 1
        ushort8v h = *(const ushort8v*)(Xb + (size_t)v * XS + f0);
#pragma unroll
        for (int u = 0; u < VW; u++) acc[u] = bf2f(h[u]);
    }

    const int beg = rowptr[v], end = rowptr[v + 1];
    for (int jb = beg; jb < end; jb += 64) {
        const int nj = min(64, end - jb);
        int ec = 0;
        if (lane < nj) ec = (int)col[jb + lane];
        for (int e = 0; e < nj; e += SLOTS * UNR) {
            int cs[UNR];
            bool vs[UNR];
#pragma unroll
            for (int u = 0; u < UNR; u++) {
                int srcl = e + u * SLOTS + slot;
                vs[u] = act && (srcl < nj);
                cs[u] = __shfl(ec, srcl & 63);
            }
            ushort8v xv[UNR];
#pragma unroll
            for (int u = 0; u < UNR; u++) {
                xv[u] = zero8();
                if (vs[u]) xv[u] = *(const ushort8v*)(Xb + (size_t)cs[u] * XS + f0);
            }
#pragma unroll
            for (int u = 0; u < UNR; u++)
#pragma unroll
                for (int k2 = 0; k2 < VW; k2++)
                    acc[k2] += bf2f(xv[u][k2]);
        }
    }

    // reduce across slots (valid on slot 0)
#pragma unroll
    for (int k2 = 0; k2 < VW; k2++) {
        float t2 = acc[k2];
#pragma unroll
        for (int s2 = 1; s2 < SLOTS; s2++) t2 += __shfl(acc[k2], chunk + s2 * CHUNKS);
        acc[k2] = t2;
    }

    if (slot == 0 && f0 < KPf) {
        ushort8v h8, l8;
#pragma unroll
        for (int u = 0; u < VW; u++) {
            unsigned short hh = f2bf(acc[u]);
            h8[u] = hh;
            l8[u] = f2bf(acc[u] - bf2f(hh));
        }
        *(ushort8v*)(Th + (size_t)v * KPf + f0) = h8;   // pad lanes write exact zeros
        *(ushort8v*)(Tl + (size_t)v * KPf + f0) = l8;
    }
}

// ---------------- W preprocess: transpose + split into bf16 hi/lo, k-padded to KP --------

__global__ __launch_bounds__(256) void k_wsplit(const float* __restrict__ W,
                                                unsigned short* __restrict__ Wth,
                                                unsigned short* __restrict__ Wtl,
                                                int K, int Fout, int KP) {
    int i = blockIdx.x * blockDim.x + threadIdx.x;
    if (i >= Fout * KP) return;
    int c = i / KP, k = i - c * KP;
    float w = (k < K) ? W[(size_t)k * Fout + c] : 0.f;
    unsigned short h = f2bf(w);
    Wth[i] = h;
    Wtl[i] = f2bf(w - bf2f(h));
}

// ---------------- split-bf16 MFMA GEMM with row scaling (round-15 structure, plane-A) ----
// 128-row x CT-col tile (CT = 32*NJW), 4 waves 2x2, wave = 4 x NJW tiles of 16x16x32.
// A pre-split bf16 hi/lo planes (split done in gather) -> staging is pure reg->LDS copy.
// D = Al*Bh + Ah*Bl + Ah*Bh. X' = relu(dinv[row]*(S@W)+bias).
// MODE 0: store bf16 Y' = dinv[row]*X' (row stride CSbf, pad cols zeroed).
// MODE 1: per-graph max pool of X' via atomicMax (f32 G).

template <int NJW, int MODE>
__global__ __launch_bounds__(256) void k_gemm_mfma(
    const unsigned short* __restrict__ Ahp, const unsigned short* __restrict__ Alp, int KPf,
    const unsigned short* __restrict__ Bth, const unsigned short* __restrict__ Btl,
    const float* __restrict__ bias, const float* __restrict__ dinvp,
    unsigned short* __restrict__ Cb, int CSbf,
    const int* __restrict__ batch, float* __restrict__ G,
    int N, int KP, int Fout) {
    constexpr int CT = 32 * NJW;                 // 96 or 160
    constexpr int BIT = (2 * CT + 255) / 256;    // B staging iterations (1 or 2)
    __shared__ unsigned short sAh[128 * LDST];
    __shared__ unsigned short sAl[128 * LDST];
    __shared__ unsigned short sBh[CT * LDST];
    __shared__ unsigned short sBl[CT * LDST];
    __shared__ int sBatch[128];

    const int t = threadIdx.x;
    const int r0 = blockIdx.x * 128;
    const int c0 = blockIdx.y * CT;
    const int lane = t & 63;
    const int wv = t >> 6;
    const int wrow = (wv >> 1) * 64;
    const int wcol = (wv & 1) * (16 * NJW);
    const int l15 = lane & 15;
    const int lk = (lane >> 4) * 8;
    const int nt = KP >> 5;

    const int srow = t >> 1;
    const int sseg = (t & 1) << 4;

    if (MODE == 1 && t < 128) sBatch[t] = (r0 + t < N) ? batch[r0 + t] : -1;

    const bool arow_ok = (r0 + srow) < N;
    const unsigned short* ahRow = Ahp + (size_t)(r0 + srow) * KPf;
    const unsigned short* alRow = Alp + (size_t)(r0 + srow) * KPf;

    ushort8v rah0, rah1, ral0, ral1;
    ushort8v rbh[BIT][2], rbl[BIT][2];

    auto gload = [&](int kk) {
        int gk = kk + sseg;
        bool ok0 = arow_ok && (gk < KPf);
        bool ok1 = arow_ok && (gk + 8 < KPf);
        rah0 = ok0 ? *(const ushort8v*)(ahRow + gk) : zero8();
        rah1 = ok1 ? *(const ushort8v*)(ahRow + gk + 8) : zero8();
        ral0 = ok0 ? *(const ushort8v*)(alRow + gk) : zero8();
        ral1 = ok1 ? *(const ushort8v*)(alRow + gk + 8) : zero8();
#pragma unroll
        for (int it = 0; it < BIT; it++) {
            int item = it * 256 + t;
            int brow = item >> 1;
            int bseg = (item & 1) << 4;
            rbh[it][0] = zero8(); rbh[it][1] = zero8();
            rbl[it][0] = zero8(); rbl[it][1] = zero8();
            if (brow < CT) {
                int gc = c0 + brow;
                if (gc < Fout) {
                    const unsigned short* bh = Bth + (size_t)gc * KP + kk + bseg;
                    const unsigned short* bl = Btl + (size_t)gc * KP + kk + bseg;
                    rbh[it][0] = *(const ushort8v*)bh;
                    rbh[it][1] = *(const ushort8v*)(bh + 8);
                    rbl[it][0] = *(const ushort8v*)bl;
                    rbl[it][1] = *(const ushort8v*)(bl + 8);
                }
            }
        }
    };

    auto wlds = [&]() {
        int off = srow * LDST + sseg;
        *(ushort8v*)&sAh[off] = rah0;
        *(ushort8v*)&sAh[off + 8] = rah1;
        *(ushort8v*)&sAl[off] = ral0;
        *(ushort8v*)&sAl[off + 8] = ral1;
#pragma unroll
        for (int it = 0; it < BIT; it++) {
            int item = it * 256 + t;
            int brow = item >> 1;
            int bseg = (item & 1) << 4;
            if (brow < CT) {
                int boff = brow * LDST + bseg;
                *(ushort8v*)&sBh[boff] = rbh[it][0];
                *(ushort8v*)&sBh[boff + 8] = rbh[it][1];
                *(ushort8v*)&sBl[boff] = rbl[it][0];
                *(ushort8v*)&sBl[boff + 8] = rbl[it][1];
            }
        }
    };

    f32x4 acc[4][NJW];
#pragma unroll
    for (int i = 0; i < 4; i++)
#pragma unroll
        for (int j = 0; j < NJW; j++) acc[i][j] = (f32x4){0.f, 0.f, 0.f, 0.f};

    gload(0);
    for (int tc = 0; tc < nt; ++tc) {
        wlds();
        __syncthreads();
        if (tc + 1 < nt) gload((tc + 1) * 32);   // latency hides under MFMA below
        short8v ah[4], al[4];
#pragma unroll
        for (int i = 0; i < 4; i++) {
            int ro = (wrow + i * 16 + l15) * LDST + lk;
            ah[i] = *(const short8v*)&sAh[ro];
            al[i] = *(const short8v*)&sAl[ro];
        }
#pragma unroll
        for (int j = 0; j < NJW; j++) {
            int co = (wcol + j * 16 + l15) * LDST + lk;
            short8v bh = *(const short8v*)&sBh[co];
            short8v bl = *(const short8v*)&sBl[co];
#pragma unroll
            for (int i = 0; i < 4; i++) {
                acc[i][j] = __builtin_amdgcn_mfma_f32_16x16x32_bf16(al[i], bh, acc[i][j], 0, 0, 0);
                acc[i][j] = __builtin_amdgcn_mfma_f32_16x16x32_bf16(ah[i], bl, acc[i][j], 0, 0, 0);
                acc[i][j] = __builtin_amdgcn_mfma_f32_16x16x32_bf16(ah[i], bh, acc[i][j], 0, 0, 0);
            }
        }
        __syncthreads();
    }

    // per-thread row scales (C/D layout m89-verified: col = lane&15, row = (lane>>4)*4 + reg)
    float drw[16];
#pragma unroll
    for (int i = 0; i < 4; i++)
#pragma unroll
        for (int q = 0; q < 4; q++) {
            int gr = r0 + wrow + i * 16 + (lane >> 4) * 4 + q;
            drw[i * 4 + q] = (gr < N) ? dinvp[gr] : 0.f;
        }

    if (MODE == 0) {
#pragma unroll
        for (int j = 0; j < NJW; j++) {
            int gc = c0 + wcol + j * 16 + l15;
            if (gc >= CSbf) continue;
            float bv = (gc < Fout) ? bias[gc] : 0.f;
#pragma unroll
            for (int i = 0; i < 4; i++) {
                int rb = r0 + wrow + i * 16 + (lane >> 4) * 4;
#pragma unroll
                for (int q = 0; q < 4; q++) {
                    int gr = rb + q;
                    if (gr >= N) continue;
                    float dr = drw[i * 4 + q];
                    float vv = (gc < Fout) ? fmaxf(fmaf(acc[i][j][q], dr, bv), 0.f) * dr : 0.f;
                    Cb[(size_t)gr * CSbf + gc] = f2bf(vv);
                }
            }
        }
    } else {
#pragma unroll
        for (int j = 0; j < NJW; j++) {
            int gc = c0 + wcol + j * 16 + l15;
            if (gc >= Fout) continue;
            float bv = bias[gc];
            int gcur = -1;
            float vmax = 0.f;
#pragma unroll
            for (int i = 0; i < 4; i++) {
                int lr = wrow + i * 16 + (lane >> 4) * 4;
#pragma unroll
                for (int q = 0; q < 4; q++) {
                    int g = sBatch[lr + q];
                    float vv = fmaxf(fmaf(acc[i][j][q], drw[i * 4 + q], bv), 0.f);
                    if (g < 0) continue;
                    if (g != gcur) {
                        if (gcur >= 0)
                            atomicMax((int*)&G[(size_t)gcur * Fout + gc], __float_as_int(vmax));
                        gcur = g;
                        vmax = vv;
                    } else {
                        vmax = fmaxf(vmax, vv);
                    }
                }
            }
            if (gcur >= 0) atomicMax((int*)&G[(size_t)gcur * Fout + gc], __float_as_int(vmax));
        }
    }
}

// ---------------- fc_g1: C[M,Nout] = relu(A@W + b); 2 rows x 256 cols per block ----------

__global__ __launch_bounds__(256) void k_fc1(const float* __restrict__ A,
                                             const float* __restrict__ W,
                                             const float* __restrict__ bias,
                                             float* __restrict__ C,
                                             int M, int K, int Nout) {
    __shared__ float sA[2 * 304];
    const int t = threadIdx.x;
    const int m0 = blockIdx.x * 2;
    const int oc = blockIdx.y * 256 + t;

    for (int i = t; i < 2 * K; i += 256) {
        int r = i / K, k = i - r * K;
        sA[r * 304 + k] = (m0 + r < M) ? A[(size_t)(m0 + r) * K + k] : 0.f;
    }
    __syncthreads();

    float acc0 = 0.f, acc1 = 0.f;
    int k = 0;
    for (; k + 8 <= K; k += 8) {
        float w[8];
#pragma unroll
        for (int u = 0; u < 8; u++) w[u] = W[(size_t)(k + u) * Nout + oc];
#pragma unroll
        for (int u = 0; u < 8; u++) {
            acc0 = fmaf(sA[k + u], w[u], acc0);
            acc1 = fmaf(sA[304 + k + u], w[u], acc1);
        }
    }
    for (; k < K; k++) {
        float w = W[(size_t)k * Nout + oc];
        acc0 = fmaf(sA[k], w, acc0);
        acc1 = fmaf(sA[304 + k], w, acc1);
    }
    float bv = bias[oc];
    if (m0 < M) C[(size_t)m0 * Nout + oc] = fmaxf(acc0 + bv, 0.f);
    if (m0 + 1 < M) C[(size_t)(m0 + 1) * Nout + oc] = fmaxf(acc1 + bv, 0.f);
}

// ---------------- fc_g2: split-K partial (KS=256) + deterministic reduce ----------------

__global__ __launch_bounds__(256) void k_fc2p(const float* __restrict__ A,
                                              const float* __restrict__ W,
                                              float* __restrict__ P,
                                              int M, int K, int Nout) {
    __shared__ float sA[2 * 256];
    const int t = threadIdx.x;
    const int m0 = blockIdx.x * 2;
    const int sk = blockIdx.y;
    const int k0 = sk * 256;
    const int row = t >> 7;
    const int oc = t & 127;

    for (int i = t; i < 2 * 256; i += 256) {
        int r = i >> 8, k = i & 255;
        sA[i] = (m0 + r < M) ? A[(size_t)(m0 + r) * K + k0 + k] : 0.f;
    }
    __syncthreads();

    const float* a = sA + row * 256;
    float acc = 0.f;
    for (int k = 0; k < 256; k += 8) {
        float w[8];
#pragma unroll
        for (int u = 0; u < 8; u++) w[u] = W[(size_t)(k0 + k + u) * Nout + oc];
#pragma unroll
        for (int u = 0; u < 8; u++) acc = fmaf(a[k + u], w[u], acc);
    }
    int m = m0 + row;
    if (m < M) P[((size_t)sk * M + m) * Nout + oc] = acc;
}

__global__ __launch_bounds__(256) void k_fc2r(const float* __restrict__ P,
                                              const float* __restrict__ bias,
                                              float* __restrict__ C,
                                              int M, int Nout, int SK) {
    int i = blockIdx.x * blockDim.x + threadIdx.x;
    if (i >= M * Nout) return;
    int oc = i % Nout;
    float acc = bias[oc];
    for (int s2 = 0; s2 < SK; s2++) acc += P[(size_t)s2 * M * Nout + i];
    C[i] = acc;
}

// ---------------- launch ----------------

extern "C" void kernel_launch(void* const* d_in, const int* in_sizes, int n_in,
                              void* d_out, int out_size, void* d_ws, size_t ws_size,
                              hipStream_t stream) {
    const float* x     = (const float*)d_in[0];
    const int*   ei    = (const int*)d_in[1];
    const int*   batch = (const int*)d_in[2];
    const float* W1 = (const float*)d_in[3];
    const float* b1 = (const float*)d_in[4];
    const float* W2 = (const float*)d_in[5];
    const float* b2 = (const float*)d_in[6];
    const float* W3 = (const float*)d_in[7];
    const float* b3 = (const float*)d_in[8];
    const float* Wg1 = (const float*)d_in[9];
    const float* bg1 = (const float*)d_in[10];
    const float* Wg2 = (const float*)d_in[11];
    const float* bg2 = (const float*)d_in[12];

    const int N  = in_sizes[2];          // 50000 (< 65536: col fits uint16)
    const int E  = in_sizes[1] / 2;      // 800000
    const int F1 = in_sizes[4];          // 75
    const int F2 = in_sizes[6];          // 150
    const int F3 = in_sizes[8];          // 300
    const int H1 = in_sizes[10];         // 1024
    const int OC = in_sizes[12];         // 128
    const int NG = out_size / OC;        // 256
    const int FIN = in_sizes[3] / F1;    // 75

    const int KP1 = 96,  KPf1 = 80;      // K=75 padded (GEMM loop / A-plane stride)
    const int KP3 = 160, KPf3 = 152;     // K=150 padded
    const int XS0 = 80;                  // x bf16 (pre-scaled) row stride
    const int HS1 = 80;                  // Y1 bf16 row stride
    const int HS2 = 152;                 // Y2 bf16 row stride

    const int* src = ei;
    const int* dst = ei + E;

    char* base = (char*)d_ws;
    size_t off = 0;
    auto alloc = [&](size_t bytes) -> void* {
        void* p = base + off;
        off = (off + bytes + 255) & ~(size_t)255;
        return p;
    };
    int*   cnt    = (int*)alloc((size_t)N * 4);
    int*   fill   = (int*)alloc((size_t)N * 4);
    int*   rowptr = (int*)alloc((size_t)(N + 1) * 4);
    float* dinv   = (float*)alloc((size_t)N * 4);
    int*   bsum   = (int*)alloc(256 * 4);
    unsigned short* col = (unsigned short*)alloc((size_t)E * 2);
    unsigned short* W1th = (unsigned short*)alloc((size_t)F1 * KP1 * 2);
    unsigned short* W1tl = (unsigned short*)alloc((size_t)F1 * KP1 * 2);
    unsigned short* W2th = (unsigned short*)alloc((size_t)F2 * KP1 * 2);
    unsigned short* W2tl = (unsigned short*)alloc((size_t)F2 * KP1 * 2);
    unsigned short* W3th = (unsigned short*)alloc((size_t)F3 * KP3 * 2);
    unsigned short* W3tl = (unsigned short*)alloc((size_t)F3 * KP3 * 2);
    float* Gb  = (float*)alloc((size_t)NG * F3 * 4);
    float* g1  = (float*)alloc((size_t)NG * H1 * 4);
    float* P2  = (float*)alloc((size_t)4 * NG * OC * 4);                // split-K partials
    unsigned short* TgH = (unsigned short*)alloc((size_t)N * KPf3 * 2); // 15.2 MB hi plane
    unsigned short* TgL = (unsigned short*)alloc((size_t)N * KPf3 * 2); // 15.2 MB lo plane
    unsigned short* Xb  = (unsigned short*)alloc((size_t)N * XS0 * 2);  // 8 MB bf16 scaled x
    unsigned short* H1b = (unsigned short*)alloc((size_t)N * HS1 * 2);  // 8 MB bf16
    unsigned short* H2b = (unsigned short*)alloc((size_t)N * HS2 * 2);  // 15.2 MB bf16

    hipMemsetAsync(cnt, 0, (size_t)N * 4, stream);
    hipMemsetAsync(Gb, 0, (size_t)NG * F3 * 4, stream);

    // ---- CSR ----
    k_count<<<ceil_div_i(E, 256), 256, 0, stream>>>(dst, E, cnt);
    k_dinv<<<ceil_div_i(N, 256), 256, 0, stream>>>(cnt, dinv, N);
    int NB = ceil_div_i(N, SCAN_B);
    k_scan1<<<NB, 256, 0, stream>>>(cnt, rowptr, bsum, N);
    k_scan2<<<1, 256, 0, stream>>>(bsum, NB);
    k_scan3<<<ceil_div_i(N, 256), 256, 0, stream>>>(rowptr, bsum, fill, N, E);
    k_fill<<<ceil_div_i(E, 256), 256, 0, stream>>>(src, dst, E, fill, col);

    // ---- weight splits + scaled-x (small) ----
    k_wsplit<<<ceil_div_i((long long)F1 * KP1, 256), 256, 0, stream>>>(W1, W1th, W1tl, FIN, F1, KP1);
    k_wsplit<<<ceil_div_i((long long)F2 * KP1, 256), 256, 0, stream>>>(W2, W2th, W2tl, F1, F2, KP1);
    k_wsplit<<<ceil_div_i((long long)F3 * KP3, 256), 256, 0, stream>>>(W3, W3th, W3tl, F2, F3, KP3);
    k_xscale<<<ceil_div_i((long long)N * XS0, 256), 256, 0, stream>>>(x, dinv, Xb, N, FIN, XS0);

    dim3 blk(256);
    int gw = ceil_div_i(N, 4);
    int gx = ceil_div_i(N, 128);

    // conv1: gather Xb (10 chunks x 6 slots) -> TgH/TgL stride 80; GEMM CT=96 covers 75
    k_gather_s<10, 6, 2><<<gw, blk, 0, stream>>>(Xb, rowptr, col, TgH, TgL, N, XS0, KPf1);
    {
        dim3 g(gx, 1);
        k_gemm_mfma<3, 0><<<g, blk, 0, stream>>>(TgH, TgL, KPf1, W1th, W1tl, b1, dinv,
                                                 H1b, HS1, nullptr, nullptr, N, KP1, F1);
    }
    // conv2: gather Y1 -> TgH/TgL stride 80; GEMM CT=160 covers 150
    k_gather_s<10, 6, 2><<<gw, blk, 0, stream>>>(H1b, rowptr, col, TgH, TgL, N, HS1, KPf1);
    {
        dim3 g(gx, 1);
        k_gemm_mfma<5, 0><<<g, blk, 0, stream>>>(TgH, TgL, KPf1, W2th, W2tl, b2, dinv,
                                                 H2b, HS2, nullptr, nullptr, N, KP1, F2);
    }
    // conv3: gather Y2 (19 chunks x 3 slots) -> stride 152; GEMM CT=160 x2, fused pool
    k_gather_s<19, 3, 4><<<gw, blk, 0, stream>>>(H2b, rowptr, col, TgH, TgL, N, HS2, KPf3);
    {
        dim3 g(gx, 2);
        k_gemm_mfma<5, 1><<<g, blk, 0, stream>>>(TgH, TgL, KPf3, W3th, W3tl, b3, dinv,
                                                 nullptr, 0, batch, Gb, N, KP3, F3);
    }

    // fc_g1: 2 rows x 256 cols per block -> grid (128, 4) = 512 blocks
    {
        dim3 g(ceil_div_i(NG, 2), H1 / 256);
        k_fc1<<<g, 256, 0, stream>>>(Gb, Wg1, bg1, g1, NG, F3, H1);
    }
    // fc_g2: split-K=4 partials (512 blocks) + deterministic reduce
    {
        dim3 g(ceil_div_i(NG, 2), 4);
        k_fc2p<<<g, 256, 0, stream>>>(g1, Wg2, P2, NG, H1, OC);
        k_fc2r<<<ceil_div_i((long long)NG * OC, 256), 256, 0, stream>>>(
            P2, bg2, (float*)d_out, NG, OC, 4);
    }
}